// Round 21
// baseline (47.598 us; speedup 1.0000x reference)
//
#include <hip/hip_runtime.h>

// R22 = SLOPE-TEST measurement round. Kernel is R21 byte-for-byte (best:
// 26.07us). kernel_launch launches it TWICE back-to-back (deterministic:
// identical inputs -> identical output both times; graph-safe: two sequential
// nodes). Decomposes dur_us = F + n*W: R21 gave F+W=26.07; this round gives
// F+2W. If ~34-38: W~8-12 matches pipe model, F~15 harness floor -> near done.
// If ~50: W~24, pipe model wrong -> dig into phase B. If ~30: W~4, all fixed
// overhead -> declare.
//
// out[b,o] = sum_h W2[o,h]*leaky(h) + b2[o],  h = W1[o]·x[b] + b1[o]
// leaky(t) = 0.6t + 0.4|t|

#define B_DIM 32768
#define I_DIM 16
#define O_DIM 16
#define H_DIM 512

typedef _Float16 f16x4 __attribute__((ext_vector_type(4)));
typedef _Float16 f16x8 __attribute__((ext_vector_type(8)));
typedef __fp16   h16x2 __attribute__((ext_vector_type(2)));   // cvt_pkrtz native
typedef float    f32x4 __attribute__((ext_vector_type(4)));
typedef int      i32x2 __attribute__((ext_vector_type(2)));
typedef int      i32x4 __attribute__((ext_vector_type(4)));

// 256 blocks x 512 thr (8 waves), 1 block/CU. o = blk&15, grp = blk>>4 (16).
// Block covers 128 b-tiles in two halves of 64; wave w: 8 tiles per half.
__global__ __launch_bounds__(512, 2) void mlp_fused(
    const float* __restrict__ x, const float* __restrict__ W1,
    const float* __restrict__ b1, const float* __restrict__ W2,
    const float* __restrict__ b2, float* __restrict__ out) {
    __shared__ f16x8 sm_a1[1024];     // [p][lane] stage1-A pairs   16 KiB
    __shared__ f16x8 sm_w2[1024];     // [p][lane] stage2-B (0.4x)  16 KiB
    __shared__ float sm_b1[512];      //  2 KiB
    __shared__ f32x4 red4[512];       //  8 KiB (v partials)
    __shared__ float red[512];        //  2 KiB (c0 partials)
    __shared__ float v_sm[16];
    __shared__ float c_sm;

    const int tid = threadIdx.x;
    const int o   = blockIdx.x & 15;
    const int grp = blockIdx.x >> 4;
    const float* W1o = W1 + (size_t)o * H_DIM * I_DIM;
    const float* W2o = W2 + (size_t)o * H_DIM;
    const float* b1o = b1 + (size_t)o * H_DIM;

    const int lane = tid & 63, w = tid >> 6;
    const int col = lane & 15, kg = lane >> 4;

    // ---- phase A: stage fragments + fused v-partials ----
    f32x4 vpart = {0.f, 0.f, 0.f, 0.f};
#pragma unroll
    for (int i = 0; i < 2; ++i) {
        const int e = tid + 512 * i;          // 0..1023 = [p][lane]
        const int l = e & 63, p = e >> 6;
        const int row = l & 15, kgs = l >> 4;
        const float* a_base = W1o + ((size_t)(2 * p * 16 + row) * I_DIM + kgs * 4);
        const f32x4 a0 = *reinterpret_cast<const f32x4*>(a_base);
        const f32x4 a1v = *reinterpret_cast<const f32x4*>(a_base + 16 * I_DIM);
        f16x8 va;
#pragma unroll
        for (int j = 0; j < 4; ++j) { va[j] = (_Float16)a0[j]; va[4 + j] = (_Float16)a1v[j]; }
        sm_a1[e] = va;
        const float w2a = W2o[2 * p * 16 + row];
        const float w2b = W2o[2 * p * 16 + 16 + row];
#pragma unroll
        for (int j = 0; j < 4; ++j)
            vpart[j] = fmaf(w2b, a1v[j], fmaf(w2a, a0[j], vpart[j]));
        const float* w_base = W2o + p * 32 + kgs * 4;
        const f32x4 w0 = *reinterpret_cast<const f32x4*>(w_base);
        const f32x4 w1v = *reinterpret_cast<const f32x4*>(w_base + 16);
        f16x8 vw;
#pragma unroll
        for (int j = 0; j < 4; ++j) {
            vw[j]     = (_Float16)(0.4f * w0[j]);
            vw[4 + j] = (_Float16)(0.4f * w1v[j]);
        }
        sm_w2[e] = vw;
    }
    {
        const float b1v = b1o[tid];
        sm_b1[tid] = b1v;
        red[tid]   = W2o[tid] * b1v;          // c0 partial
        red4[tid]  = vpart;                   // v partial (cols kg*4..+4)
    }

    // hoist half-0 x loads: HBM latency hides under phase-A reduce
    f16x4 xf0[8];
    {
        const int tile0 = grp * 128 + w * 8;
#pragma unroll
        for (int t = 0; t < 8; ++t) {
            const f32x4 xv = *reinterpret_cast<const f32x4*>(
                x + (size_t)((tile0 + t) * 16 + col) * I_DIM + kg * 4);
            h16x2 q0 = __builtin_amdgcn_cvt_pkrtz(xv[0], xv[1]);
            h16x2 q1 = __builtin_amdgcn_cvt_pkrtz(xv[2], xv[3]);
            i32x2 xi; xi[0] = __builtin_bit_cast(int, q0); xi[1] = __builtin_bit_cast(int, q1);
            xf0[t] = __builtin_bit_cast(f16x4, xi);
        }
    }
    __syncthreads();

    // wave 0: reduce v (f32x4 per kg-group) and c0 together
    if (tid < 64) {
        f32x4 s = red4[tid];
#pragma unroll
        for (int k = 1; k < 8; ++k) s += red4[tid + 64 * k];
#pragma unroll
        for (int m = 1; m <= 8; m <<= 1) {
#pragma unroll
            for (int c = 0; c < 4; ++c) s[c] += __shfl_xor(s[c], m, 64);
        }
        if ((tid & 15) == 0) {
            const int kgw = tid >> 4;
#pragma unroll
            for (int j = 0; j < 4; ++j) v_sm[kgw * 4 + j] = 0.6f * s[j];
        }
        float cs = 0.f;
#pragma unroll
        for (int k = 0; k < 8; ++k) cs += red[tid + 64 * k];
#pragma unroll
        for (int m = 1; m <= 32; m <<= 1) cs += __shfl_xor(cs, m, 64);
        if (tid == 0) c_sm = 0.6f * cs + b2[o];
    }
    __syncthreads();

    // ---- phase B (R20 body; half 0 uses hoisted xf0) ----
    for (int half = 0; half < 2; ++half) {
        const int tile0 = grp * 128 + half * 64 + w * 8;

        f16x4 xf[8];
        if (half == 0) {
#pragma unroll
            for (int t = 0; t < 8; ++t) xf[t] = xf0[t];
        } else {
#pragma unroll
            for (int t = 0; t < 8; ++t) {
                const f32x4 xv = *reinterpret_cast<const f32x4*>(
                    x + (size_t)((tile0 + t) * 16 + col) * I_DIM + kg * 4);
                h16x2 q0 = __builtin_amdgcn_cvt_pkrtz(xv[0], xv[1]);
                h16x2 q1 = __builtin_amdgcn_cvt_pkrtz(xv[2], xv[3]);
                i32x2 xi; xi[0] = __builtin_bit_cast(int, q0); xi[1] = __builtin_bit_cast(int, q1);
                xf[t] = __builtin_bit_cast(f16x4, xi);
            }
        }

        f16x4 vlf;
#pragma unroll
        for (int j = 0; j < 4; ++j) vlf[j] = (_Float16)v_sm[kg * 4 + j];
        const float c0 = c_sm;
        const f32x4 linC = {c0, c0, c0, c0};

        f32x4 acc[8];
#pragma unroll
        for (int t = 0; t < 8; ++t)
            acc[t] = __builtin_amdgcn_mfma_f32_16x16x16f16(xf[t], vlf, linC, 0, 0, 0);

#pragma unroll 2
        for (int p = 0; p < 16; ++p) {
            const f16x8 a1pair = sm_a1[p * 64 + lane];
            const f16x4 A1a = __builtin_shufflevector(a1pair, a1pair, 0, 1, 2, 3);
            const f16x4 A1b = __builtin_shufflevector(a1pair, a1pair, 4, 5, 6, 7);
            const f16x8 W2f = sm_w2[p * 64 + lane];
            const f32x4 bC0 = *reinterpret_cast<const f32x4*>(&sm_b1[p * 32 + kg * 4]);
            const f32x4 bC1 = *reinterpret_cast<const f32x4*>(&sm_b1[p * 32 + 16 + kg * 4]);
#pragma unroll
            for (int t = 0; t < 8; ++t) {
                f32x4 d0 = __builtin_amdgcn_mfma_f32_16x16x16f16(A1a, xf[t], bC0, 0, 0, 0);
                f32x4 d1 = __builtin_amdgcn_mfma_f32_16x16x16f16(A1b, xf[t], bC1, 0, 0, 0);
                h16x2 p0 = __builtin_amdgcn_cvt_pkrtz(fabsf(d0[0]), fabsf(d0[1]));
                h16x2 p1 = __builtin_amdgcn_cvt_pkrtz(fabsf(d0[2]), fabsf(d0[3]));
                h16x2 p2 = __builtin_amdgcn_cvt_pkrtz(fabsf(d1[0]), fabsf(d1[1]));
                h16x2 p3 = __builtin_amdgcn_cvt_pkrtz(fabsf(d1[2]), fabsf(d1[3]));
                i32x4 ai;
                ai[0] = __builtin_bit_cast(int, p0); ai[1] = __builtin_bit_cast(int, p1);
                ai[2] = __builtin_bit_cast(int, p2); ai[3] = __builtin_bit_cast(int, p3);
                f16x8 A2 = __builtin_bit_cast(f16x8, ai);
                acc[t] = __builtin_amdgcn_mfma_f32_16x16x32_f16(A2, W2f, acc[t], 0, 0, 0);
            }
        }

        // acc[t][r]: b_local = kg*4 + r (all 16 cols identical).
        if (col < 4) {
#pragma unroll
            for (int t = 0; t < 8; ++t) {
                float v = (col == 0) ? acc[t][0] : (col == 1) ? acc[t][1]
                        : (col == 2) ? acc[t][2] : acc[t][3];
                out[(size_t)((tile0 + t) * 16 + kg * 4 + col) * O_DIM + o] = v;
            }
        }
    }
}

extern "C" void kernel_launch(void* const* d_in, const int* in_sizes, int n_in,
                              void* d_out, int out_size, void* d_ws, size_t ws_size,
                              hipStream_t stream) {
    const float* x  = (const float*)d_in[0];
    const float* W1 = (const float*)d_in[1];
    const float* b1 = (const float*)d_in[2];
    const float* W2 = (const float*)d_in[3];
    const float* b2 = (const float*)d_in[4];
    float* out = (float*)d_out;

    // SLOPE TEST: identical kernel twice. dur_us(R22) - dur_us(R21) = W
    // (true per-dispatch time); F = 26.07 - W = fixed overhead.
    mlp_fused<<<256, 512, 0, stream>>>(x, W1, b1, W2, b2, out);
    mlp_fused<<<256, 512, 0, stream>>>(x, W1, b1, W2, b2, out);
}

// Round 22
// 26.328 us; speedup vs baseline: 1.8079x; 1.8079x over previous
//
#include <hip/hip_runtime.h>

// out[b,o] = sum_h W2[o,h]*leaky(h) + b2[o],  h = W1[o]·x[b] + b1[o]
// leaky(t) = 0.6t + 0.4|t|
//   out[b,o] = 0.6(v[o]·x[b] + c0[o]) + b2[o] + sum_h (0.4 W2[o,h])|h|
// R23: slope test (R22) measured W=21.5us kernel / F=4.5us fixed. Issue floor
// is ~5us -> waves stall ~75% at 2 waves/SIMD. This round: 256 blocks x 1024
// thr = 16 waves/block, 1 block/CU -> 4 waves/SIMD (2x stall-hiding) while
// keeping R21's 1/CU phase-A amortization. Wave w: 4 tiles per half.
// Phase B per-tile body identical to R21 (proven no-spill). (1024,1) ->
// 128-VGPR cap (empirical rule: cap=512/waves-per-EU; 16w/4SIMD=4 -> 128).

#define B_DIM 32768
#define I_DIM 16
#define O_DIM 16
#define H_DIM 512

typedef _Float16 f16x4 __attribute__((ext_vector_type(4)));
typedef _Float16 f16x8 __attribute__((ext_vector_type(8)));
typedef __fp16   h16x2 __attribute__((ext_vector_type(2)));   // cvt_pkrtz native
typedef float    f32x4 __attribute__((ext_vector_type(4)));
typedef int      i32x2 __attribute__((ext_vector_type(2)));
typedef int      i32x4 __attribute__((ext_vector_type(4)));

// 256 blocks x 1024 thr (16 waves), 1 block/CU. o = blk&15, grp = blk>>4 (16).
// Block covers 128 b-tiles in two halves of 64; wave w: 4 tiles per half.
__global__ __launch_bounds__(1024, 1) void mlp_fused(
    const float* __restrict__ x, const float* __restrict__ W1,
    const float* __restrict__ b1, const float* __restrict__ W2,
    const float* __restrict__ b2, float* __restrict__ out) {
    __shared__ f16x8 sm_a1[1024];     // [p][lane] stage1-A pairs   16 KiB
    __shared__ f16x8 sm_w2[1024];     // [p][lane] stage2-B (0.4x)  16 KiB
    __shared__ float sm_b1[512];      //  2 KiB
    __shared__ f32x4 red4[1024];      // 16 KiB (v partials)
    __shared__ float red[1024];       //  4 KiB (c0 partials)
    __shared__ float v_sm[16];
    __shared__ float c_sm;

    const int tid = threadIdx.x;
    const int o   = blockIdx.x & 15;
    const int grp = blockIdx.x >> 4;
    const float* W1o = W1 + (size_t)o * H_DIM * I_DIM;
    const float* W2o = W2 + (size_t)o * H_DIM;
    const float* b1o = b1 + (size_t)o * H_DIM;

    const int lane = tid & 63, w = tid >> 6;
    const int col = lane & 15, kg = lane >> 4;

    // ---- phase A: stage fragments + fused v-partials (one pass, 1024 thr) ----
    f32x4 vpart = {0.f, 0.f, 0.f, 0.f};
    {
        const int e = tid;                    // 0..1023 = [p][lane]
        const int l = e & 63, p = e >> 6;
        const int row = l & 15, kgs = l >> 4;
        // stage1-A pair: rows h0=2p*16+row, h1=h0+16; cols kgs*4..+4
        const float* a_base = W1o + ((size_t)(2 * p * 16 + row) * I_DIM + kgs * 4);
        const f32x4 a0 = *reinterpret_cast<const f32x4*>(a_base);
        const f32x4 a1v = *reinterpret_cast<const f32x4*>(a_base + 16 * I_DIM);
        f16x8 va;
#pragma unroll
        for (int j = 0; j < 4; ++j) { va[j] = (_Float16)a0[j]; va[4 + j] = (_Float16)a1v[j]; }
        sm_a1[e] = va;
        // fused v-partial
        const float w2a = W2o[2 * p * 16 + row];
        const float w2b = W2o[2 * p * 16 + 16 + row];
#pragma unroll
        for (int j = 0; j < 4; ++j)
            vpart[j] = fmaf(w2b, a1v[j], fmaf(w2a, a0[j], vpart[j]));
        // stage2-B: k=kgs*8+j -> h = p*32 + ((j>>2)&1)*16 + kgs*4 + (j&3)
        const float* w_base = W2o + p * 32 + kgs * 4;
        const f32x4 w0 = *reinterpret_cast<const f32x4*>(w_base);
        const f32x4 w1v = *reinterpret_cast<const f32x4*>(w_base + 16);
        f16x8 vw;
#pragma unroll
        for (int j = 0; j < 4; ++j) {
            vw[j]     = (_Float16)(0.4f * w0[j]);
            vw[4 + j] = (_Float16)(0.4f * w1v[j]);
        }
        sm_w2[e] = vw;
        red4[tid] = vpart;
        if (tid < 512) {
            const float b1v = b1o[tid];
            sm_b1[tid] = b1v;
            red[tid]   = W2o[tid] * b1v;      // c0 partial
        } else {
            red[tid] = 0.f;
        }
    }

    // hoist half-0 x loads: HBM latency hides under phase-A reduce
    f16x4 xf0[4];
    {
        const int tile0 = grp * 128 + w * 4;
#pragma unroll
        for (int t = 0; t < 4; ++t) {
            const f32x4 xv = *reinterpret_cast<const f32x4*>(
                x + (size_t)((tile0 + t) * 16 + col) * I_DIM + kg * 4);
            h16x2 q0 = __builtin_amdgcn_cvt_pkrtz(xv[0], xv[1]);
            h16x2 q1 = __builtin_amdgcn_cvt_pkrtz(xv[2], xv[3]);
            i32x2 xi; xi[0] = __builtin_bit_cast(int, q0); xi[1] = __builtin_bit_cast(int, q1);
            xf0[t] = __builtin_bit_cast(f16x4, xi);
        }
    }
    __syncthreads();

    // wave 0: reduce v (f32x4 per kg-group) and c0 together
    if (tid < 64) {
        f32x4 s = red4[tid];
#pragma unroll
        for (int k = 1; k < 16; ++k) s += red4[tid + 64 * k];
#pragma unroll
        for (int m = 1; m <= 8; m <<= 1) {
#pragma unroll
            for (int c = 0; c < 4; ++c) s[c] += __shfl_xor(s[c], m, 64);
        }
        if ((tid & 15) == 0) {
            const int kgw = tid >> 4;
#pragma unroll
            for (int j = 0; j < 4; ++j) v_sm[kgw * 4 + j] = 0.6f * s[j];
        }
        float cs = 0.f;
#pragma unroll
        for (int k = 0; k < 16; ++k) cs += red[tid + 64 * k];
#pragma unroll
        for (int m = 1; m <= 32; m <<= 1) cs += __shfl_xor(cs, m, 64);
        if (tid == 0) c_sm = 0.6f * cs + b2[o];
    }
    __syncthreads();

    // ---- phase B (R21 per-tile body; 4 tiles/wave/half) ----
    for (int half = 0; half < 2; ++half) {
        const int tile0 = grp * 128 + half * 64 + w * 4;

        f16x4 xf[4];
        if (half == 0) {
#pragma unroll
            for (int t = 0; t < 4; ++t) xf[t] = xf0[t];
        } else {
#pragma unroll
            for (int t = 0; t < 4; ++t) {
                const f32x4 xv = *reinterpret_cast<const f32x4*>(
                    x + (size_t)((tile0 + t) * 16 + col) * I_DIM + kg * 4);
                h16x2 q0 = __builtin_amdgcn_cvt_pkrtz(xv[0], xv[1]);
                h16x2 q1 = __builtin_amdgcn_cvt_pkrtz(xv[2], xv[3]);
                i32x2 xi; xi[0] = __builtin_bit_cast(int, q0); xi[1] = __builtin_bit_cast(int, q1);
                xf[t] = __builtin_bit_cast(f16x4, xi);
            }
        }

        f16x4 vlf;
#pragma unroll
        for (int j = 0; j < 4; ++j) vlf[j] = (_Float16)v_sm[kg * 4 + j];
        const float c0 = c_sm;
        const f32x4 linC = {c0, c0, c0, c0};

        f32x4 acc[4];
#pragma unroll
        for (int t = 0; t < 4; ++t)
            acc[t] = __builtin_amdgcn_mfma_f32_16x16x16f16(xf[t], vlf, linC, 0, 0, 0);

#pragma unroll 2
        for (int p = 0; p < 16; ++p) {
            const f16x8 a1pair = sm_a1[p * 64 + lane];
            const f16x4 A1a = __builtin_shufflevector(a1pair, a1pair, 0, 1, 2, 3);
            const f16x4 A1b = __builtin_shufflevector(a1pair, a1pair, 4, 5, 6, 7);
            const f16x8 W2f = sm_w2[p * 64 + lane];
            const f32x4 bC0 = *reinterpret_cast<const f32x4*>(&sm_b1[p * 32 + kg * 4]);
            const f32x4 bC1 = *reinterpret_cast<const f32x4*>(&sm_b1[p * 32 + 16 + kg * 4]);
#pragma unroll
            for (int t = 0; t < 4; ++t) {
                f32x4 d0 = __builtin_amdgcn_mfma_f32_16x16x16f16(A1a, xf[t], bC0, 0, 0, 0);
                f32x4 d1 = __builtin_amdgcn_mfma_f32_16x16x16f16(A1b, xf[t], bC1, 0, 0, 0);
                h16x2 p0 = __builtin_amdgcn_cvt_pkrtz(fabsf(d0[0]), fabsf(d0[1]));
                h16x2 p1 = __builtin_amdgcn_cvt_pkrtz(fabsf(d0[2]), fabsf(d0[3]));
                h16x2 p2 = __builtin_amdgcn_cvt_pkrtz(fabsf(d1[0]), fabsf(d1[1]));
                h16x2 p3 = __builtin_amdgcn_cvt_pkrtz(fabsf(d1[2]), fabsf(d1[3]));
                i32x4 ai;
                ai[0] = __builtin_bit_cast(int, p0); ai[1] = __builtin_bit_cast(int, p1);
                ai[2] = __builtin_bit_cast(int, p2); ai[3] = __builtin_bit_cast(int, p3);
                f16x8 A2 = __builtin_bit_cast(f16x8, ai);
                acc[t] = __builtin_amdgcn_mfma_f32_16x16x32_f16(A2, W2f, acc[t], 0, 0, 0);
            }
        }

        // acc[t][r]: b_local = kg*4 + r (all 16 cols identical).
        if (col < 4) {
#pragma unroll
            for (int t = 0; t < 4; ++t) {
                float v = (col == 0) ? acc[t][0] : (col == 1) ? acc[t][1]
                        : (col == 2) ? acc[t][2] : acc[t][3];
                out[(size_t)((tile0 + t) * 16 + kg * 4 + col) * O_DIM + o] = v;
            }
        }
    }
}

extern "C" void kernel_launch(void* const* d_in, const int* in_sizes, int n_in,
                              void* d_out, int out_size, void* d_ws, size_t ws_size,
                              hipStream_t stream) {
    const float* x  = (const float*)d_in[0];
    const float* W1 = (const float*)d_in[1];
    const float* b1 = (const float*)d_in[2];
    const float* W2 = (const float*)d_in[3];
    const float* b2 = (const float*)d_in[4];
    float* out = (float*)d_out;

    mlp_fused<<<256, 1024, 0, stream>>>(x, W1, b1, W2, b2, out);
}